// Round 5
// baseline (983.488 us; speedup 1.0000x reference)
//
#include <hip/hip_runtime.h>
#include <math.h>

#define E 192
#define DI 384
#define S 16
#define R 12
#define DEPTH 4
#define P 400
#define NC 20
#define BATCH 32
#define L 401
#define NTOK (BATCH * L)   // 12832
#define CH 16
#define NCH 26             // ceil(401/16)

using short8 = __attribute__((ext_vector_type(8))) short;
using float4v = __attribute__((ext_vector_type(4))) float;

__device__ __forceinline__ float siluf(float x) {
    return x / (1.f + __expf(-x));
}
__device__ __forceinline__ float softplusf(float x) {
    return (x > 20.f) ? x : log1pf(__expf(x));
}
// f32 -> bf16 round-to-nearest-even (bit-level; no __hip_bfloat16 dep)
__device__ __forceinline__ unsigned short f2bf(float x) {
    unsigned int u = __float_as_uint(x);
    unsigned int r = 0x7fffu + ((u >> 16) & 1u);
    return (unsigned short)((u + r) >> 16);
}

// ---------------------------------------------------------------------------
// K0: patch embed + pos + depthwise conv3 + cls token  -> resid[b,l,e]
// ---------------------------------------------------------------------------
__global__ void k_embed(const float* __restrict__ imgs, const float* __restrict__ patch_w,
                        const float* __restrict__ patch_b, const float* __restrict__ cls_token,
                        const float* __restrict__ pos_embed, const float* __restrict__ cnn_w,
                        const float* __restrict__ cnn_b, float* __restrict__ resid) {
    int idx = blockIdx.x * blockDim.x + threadIdx.x;
    if (idx >= NTOK * E) return;
    int e = idx % E;
    int bl = idx / E;
    int l = bl % L;
    int b = bl / L;
    float out;
    if (l == P) {
        out = cls_token[e] + pos_embed[(size_t)P * E + e];
    } else {
        float w0 = patch_w[e * 4 + 0], w1 = patch_w[e * 4 + 1];
        float w2 = patch_w[e * 4 + 2], w3 = patch_w[e * 4 + 3];
        float pb = patch_b[e];
        const float* ib = imgs + (size_t)b * 1600;
        auto xe = [&](int ll) -> float {
            const float* ip = ib + ll * 4;
            return ip[0] * w0 + ip[1] * w1 + ip[2] * w2 + ip[3] * w3 + pb +
                   pos_embed[(size_t)ll * E + e];
        };
        float c0 = cnn_w[e * 3 + 0], c1 = cnn_w[e * 3 + 1], c2 = cnn_w[e * 3 + 2];
        float acc = cnn_b[e] + xe(l) * c1;
        if (l > 0) acc += xe(l - 1) * c0;
        if (l < P - 1) acc += xe(l + 1) * c2;
        out = acc;
    }
    resid[idx] = out;
}

// ---------------------------------------------------------------------------
// K1: (optional resid += hidden) then hn = rmsnorm(resid)*w -> bf16
// ---------------------------------------------------------------------------
template <bool ADD>
__global__ void k_rmsnorm(const float* __restrict__ hidden, float* __restrict__ resid,
                          unsigned short* __restrict__ hn, const float* __restrict__ w) {
    int wave = blockIdx.x * (blockDim.x >> 6) + (threadIdx.x >> 6);
    int lane = threadIdx.x & 63;
    if (wave >= NTOK) return;
    size_t base = (size_t)wave * E;
    float v[3];
    float ss = 0.f;
#pragma unroll
    for (int j = 0; j < 3; j++) {
        int e = lane + j * 64;
        float r = resid[base + e];
        if (ADD) {
            r += hidden[base + e];
            resid[base + e] = r;
        }
        v[j] = r;
        ss += r * r;
    }
#pragma unroll
    for (int off = 32; off > 0; off >>= 1) ss += __shfl_xor(ss, off, 64);
    float scale = rsqrtf(ss * (1.f / (float)E) + 1e-5f);
#pragma unroll
    for (int j = 0; j < 3; j++) {
        int e = lane + j * 64;
        hn[base + e] = f2bf(v[j] * scale * w[e]);
    }
}

// ---------------------------------------------------------------------------
// K_prep: all weight bf16 conversions + negA in one kernel
// segments: [0,n1): in_proj->w_in  [n1,n1+n2): x_proj->w_x
//           [..+n3): out_proj->w_out  [..+n4): negA = -exp(A_log)
// ---------------------------------------------------------------------------
__global__ void k_prep(const float* __restrict__ in_proj_w, const float* __restrict__ x_proj_w,
                       const float* __restrict__ out_proj_w, const float* __restrict__ A_log,
                       unsigned short* __restrict__ w_in, unsigned short* __restrict__ w_x,
                       unsigned short* __restrict__ w_out, float* __restrict__ negA) {
    const int n1 = DEPTH * 2 * DI * E;
    const int n2 = DEPTH * 44 * DI;
    const int n3 = DEPTH * E * DI;
    const int n4 = DEPTH * DI * S;
    int idx = blockIdx.x * blockDim.x + threadIdx.x;
    if (idx < n1) {
        w_in[idx] = f2bf(in_proj_w[idx]);
    } else if (idx < n1 + n2) {
        int i = idx - n1;
        w_x[i] = f2bf(x_proj_w[i]);
    } else if (idx < n1 + n2 + n3) {
        int i = idx - n1 - n2;
        w_out[i] = f2bf(out_proj_w[i]);
    } else if (idx < n1 + n2 + n3 + n4) {
        int i = idx - n1 - n2 - n3;
        negA[i] = -__expf(A_log[i]);
    }
}

// ---------------------------------------------------------------------------
// K2: bf16 MFMA GEMM  C[M,N](f32) = A[M,K](bf16) * W[N,K](bf16)^T
// block 256 (4 waves, 2x2 over (M,N)), tile BM x BN, BK=64.
// wave tile (BM/2) x (BN/2); MT x NT mfma tiles of 16x16 per wave.
// ---------------------------------------------------------------------------
template <int BM, int BN>
__global__ __launch_bounds__(256) void k_gemm_bf16(const unsigned short* __restrict__ A,
                                                   const unsigned short* __restrict__ W,
                                                   float* __restrict__ C, int M, int N, int K) {
    constexpr int BK = 64, PADK = BK + 8;
    constexpr int MT = BM / 32, NT = BN / 32;
    __shared__ unsigned short As[BM][PADK];
    __shared__ unsigned short Bs[BN][PADK];
    int tid = threadIdx.x;
    int m0 = blockIdx.y * BM, n0 = blockIdx.x * BN;
    int wave = tid >> 6, lane = tid & 63;
    int row16 = lane & 15, quad = lane >> 4;
    int wm0 = (wave >> 1) * (BM / 2), wn0 = (wave & 1) * (BN / 2);

    float4v acc[MT][NT];
#pragma unroll
    for (int i = 0; i < MT; i++)
#pragma unroll
        for (int j = 0; j < NT; j++) acc[i][j] = (float4v){0.f, 0.f, 0.f, 0.f};

    for (int k0 = 0; k0 < K; k0 += BK) {
        // stage A: BM x BK elems, MT passes of 256 thr x 8
#pragma unroll
        for (int p = 0; p < MT; p++) {
            int idx = (p * 256 + tid) * 8;
            int row = idx / BK, col = idx % BK;
            int gm = m0 + row;
            short8 v;
            if (gm < M)
                v = *(const short8*)&A[(size_t)gm * K + k0 + col];
            else
                v = (short8)0;
            *(short8*)&As[row][col] = v;
        }
        // stage B: BN x BK elems, NT passes
#pragma unroll
        for (int p = 0; p < NT; p++) {
            int idx = (p * 256 + tid) * 8;
            int row = idx / BK, col = idx % BK;
            int gn = n0 + row;
            short8 v;
            if (gn < N)
                v = *(const short8*)&W[(size_t)gn * K + k0 + col];
            else
                v = (short8)0;
            *(short8*)&Bs[row][col] = v;
        }
        __syncthreads();
#pragma unroll
        for (int kk = 0; kk < BK; kk += 32) {
            int koff = kk + quad * 8;
            short8 af[MT], bfr[NT];
#pragma unroll
            for (int i = 0; i < MT; i++)
                af[i] = *(const short8*)&As[wm0 + i * 16 + row16][koff];
#pragma unroll
            for (int j = 0; j < NT; j++)
                bfr[j] = *(const short8*)&Bs[wn0 + j * 16 + row16][koff];
#pragma unroll
            for (int i = 0; i < MT; i++)
#pragma unroll
                for (int j = 0; j < NT; j++)
                    acc[i][j] = __builtin_amdgcn_mfma_f32_16x16x32_bf16(af[i], bfr[j],
                                                                        acc[i][j], 0, 0, 0);
        }
        __syncthreads();
    }
    // write out: D layout row=quad*4+r, col=row16
#pragma unroll
    for (int i = 0; i < MT; i++) {
#pragma unroll
        for (int j = 0; j < NT; j++) {
#pragma unroll
            for (int r = 0; r < 4; r++) {
                int m = m0 + wm0 + i * 16 + quad * 4 + r;
                int n = n0 + wn0 + j * 16 + row16;
                if (m < M && n < N) C[(size_t)m * N + n] = acc[i][j][r];
            }
        }
    }
}

// ---------------------------------------------------------------------------
// K3: causal depthwise conv4 + SiLU over xm = xz[..., :DI] -> xc (f32 + bf16)
// ---------------------------------------------------------------------------
__global__ void k_conv(const float* __restrict__ xz, const float* __restrict__ cw,
                       const float* __restrict__ cb, float* __restrict__ xc,
                       unsigned short* __restrict__ xc_bf) {
    int idx = blockIdx.x * blockDim.x + threadIdx.x;
    if (idx >= NTOK * DI) return;
    int d = idx % DI;
    int bl = idx / DI;
    int l = bl % L;
    int b = bl / L;
    const float* base = xz + (size_t)b * L * (2 * DI) + d;
    float acc = cb[d];
#pragma unroll
    for (int k = 0; k < 4; k++) {
        int ll = l - 3 + k;
        if (ll >= 0) acc += base[(size_t)ll * (2 * DI)] * cw[d * 4 + k];
    }
    float v = siluf(acc);
    xc[idx] = v;
    xc_bf[idx] = f2bf(v);
}

// ---------------------------------------------------------------------------
// K4a: chunk-local scan, dt_proj fused, state dim split across 2 threads.
// block = 768 threads: thread t -> d = t>>1, nh = t&1 (8 states each).
// Emits per-token y_local (C.h_local + u*D) and dtcum, plus chunk h_end.
// grid (NCH, BATCH).
// ---------------------------------------------------------------------------
__global__ __launch_bounds__(768) void k_scanA(
        const float* __restrict__ xc, const float* __restrict__ xdb,
        const float* __restrict__ negA, const float* __restrict__ dtw,
        const float* __restrict__ dtb, const float* __restrict__ Dskip,
        float* __restrict__ ylocal, float* __restrict__ dtcum,
        float* __restrict__ hend) {
    int t = threadIdx.x;
    int d = t >> 1;
    int nh = t & 1;          // which half of the 16 states
    int ch = blockIdx.x;
    int b = blockIdx.y;
    int t0 = ch * CH;
    int t1 = min(t0 + CH, L);
    float a[8];
#pragma unroll
    for (int j = 0; j < 8; j++) a[j] = negA[d * S + nh * 8 + j];
    float wdt[R];
#pragma unroll
    for (int r = 0; r < R; r++) wdt[r] = dtw[d * R + r];
    float bias = dtb[d];
    float dsk = Dskip[d];
    float h[8] = {};
    float dts = 0.f;
    for (int tt = t0; tt < t1; tt++) {
        size_t tok = (size_t)b * L + tt;
        const float* row = xdb + tok * 44;   // wave-uniform -> s_loads
        float dtacc = bias;
#pragma unroll
        for (int r = 0; r < R; r++) dtacc += row[r] * wdt[r];
        float dtv = softplusf(dtacc);
        dts += dtv;
        float u = xc[tok * DI + d];
        float dtu = dtv * u;
        float y = nh ? 0.f : u * dsk;
#pragma unroll
        for (int j = 0; j < 8; j++) {
            float dA = __expf(dtv * a[j]);
            h[j] = dA * h[j] + dtu * row[R + nh * 8 + j];
            y += h[j] * row[R + S + nh * 8 + j];
        }
        y += __shfl_xor(y, 1, 64);  // combine the two state-halves
        if (nh == 0) {
            ylocal[tok * DI + d] = y;
            dtcum[tok * DI + d] = dts;
        }
    }
    size_t o = (((size_t)b * NCH + ch) * DI + d) * S + nh * 8;
#pragma unroll
    for (int j = 0; j < 8; j++) hend[o + j] = h[j];
}

// ---------------------------------------------------------------------------
// K4b: combine chunk prefixes serially (NCH chunks) -> h_init per chunk.
// ---------------------------------------------------------------------------
__global__ void k_scanB(const float* __restrict__ hend, const float* __restrict__ dtcum,
                        const float* __restrict__ negA, float* __restrict__ hinit) {
    int idx = blockIdx.x * blockDim.x + threadIdx.x;
    if (idx >= BATCH * DI) return;
    int d = idx % DI;
    int b = idx / DI;
    float a[S];
#pragma unroll
    for (int n = 0; n < S; n++) a[n] = negA[d * S + n];
    float h[S] = {};
    for (int ch = 0; ch < NCH; ch++) {
        size_t o = (((size_t)b * NCH + ch) * DI + d) * S;
#pragma unroll
        for (int n = 0; n < S; n++) hinit[o + n] = h[n];
        int tlast = min(ch * CH + CH, L) - 1;
        float dts = dtcum[((size_t)b * L + tlast) * DI + d];
#pragma unroll
        for (int n = 0; n < S; n++) h[n] = __expf(dts * a[n]) * h[n] + hend[o + n];
    }
}

// ---------------------------------------------------------------------------
// K4c: fully-parallel fixup: y = (y_local + sum_n c_n exp(a_n dtcum) h0_n)
//      * silu(z)  -> bf16. One thread per (tok,d).
// ---------------------------------------------------------------------------
__global__ void k_fixup(const float* __restrict__ xz, const float* __restrict__ xdb,
                        const float* __restrict__ negA, const float* __restrict__ hinit,
                        const float* __restrict__ ylocal, const float* __restrict__ dtcum,
                        unsigned short* __restrict__ y_bf) {
    int idx = blockIdx.x * blockDim.x + threadIdx.x;
    if (idx >= NTOK * DI) return;
    int d = idx % DI;
    int tok = idx / DI;
    int l = tok % L;
    int b = tok / L;
    int ch = l / CH;  // wave-uniform (DI divisible by 64)
    float y = ylocal[idx];
    if (ch != 0) {
        float dts = dtcum[idx];
        const float* h0 = hinit + (((size_t)b * NCH + ch) * DI + d) * S;
        const float* an = negA + d * S;
        const float* cv = xdb + (size_t)tok * 44 + R + S;
        float corr = 0.f;
#pragma unroll
        for (int n = 0; n < S; n++) corr += cv[n] * __expf(an[n] * dts) * h0[n];
        y += corr;
    }
    float z = xz[(size_t)tok * (2 * DI) + DI + d];
    y_bf[idx] = f2bf(y * siluf(z));
}

// ---------------------------------------------------------------------------
// K5: final rmsnorm of token 400 of (resid+hidden), then head matmul -> out
// ---------------------------------------------------------------------------
__global__ void k_head(const float* __restrict__ resid, const float* __restrict__ hidden,
                       const float* __restrict__ norm_f_w, const float* __restrict__ head_w,
                       const float* __restrict__ head_b, float* __restrict__ out) {
    __shared__ float v[E];
    int b = blockIdx.x;
    int lane = threadIdx.x;
    size_t base = ((size_t)b * L + P) * E;
    float loc[3];
    float ss = 0.f;
#pragma unroll
    for (int j = 0; j < 3; j++) {
        int e = lane + j * 64;
        float x = resid[base + e] + hidden[base + e];
        loc[j] = x;
        ss += x * x;
    }
#pragma unroll
    for (int off = 32; off > 0; off >>= 1) ss += __shfl_xor(ss, off, 64);
    float scale = rsqrtf(ss * (1.f / (float)E) + 1e-5f);
#pragma unroll
    for (int j = 0; j < 3; j++) {
        int e = lane + j * 64;
        v[e] = loc[j] * scale * norm_f_w[e];
    }
    __syncthreads();
    if (lane < NC) {
        float acc = head_b[lane];
        for (int e = 0; e < E; e++) acc += v[e] * head_w[lane * E + e];
        out[b * NC + lane] = acc;
    }
}

// ---------------------------------------------------------------------------
extern "C" void kernel_launch(void* const* d_in, const int* in_sizes, int n_in,
                              void* d_out, int out_size, void* d_ws, size_t ws_size,
                              hipStream_t stream) {
    const float* imgs      = (const float*)d_in[0];
    const float* patch_w   = (const float*)d_in[1];
    const float* patch_b   = (const float*)d_in[2];
    const float* cls_token = (const float*)d_in[3];
    const float* pos_embed = (const float*)d_in[4];
    const float* cnn_w     = (const float*)d_in[5];
    const float* cnn_b     = (const float*)d_in[6];
    const float* norm_w    = (const float*)d_in[7];
    const float* in_proj_w = (const float*)d_in[8];
    const float* conv_w    = (const float*)d_in[9];
    const float* conv_b    = (const float*)d_in[10];
    const float* x_proj_w  = (const float*)d_in[11];
    const float* dt_proj_w = (const float*)d_in[12];
    const float* dt_proj_b = (const float*)d_in[13];
    const float* A_log     = (const float*)d_in[14];
    const float* Dskip     = (const float*)d_in[15];
    const float* out_proj_w= (const float*)d_in[16];
    const float* norm_f_w  = (const float*)d_in[17];
    const float* head_w    = (const float*)d_in[18];
    const float* head_b    = (const float*)d_in[19];

    float* ws = (float*)d_ws;
    size_t off = 0;
    float* resid  = ws + off; off += (size_t)NTOK * E;
    float* hidden = ws + off; off += (size_t)NTOK * E;
    float* xz     = ws + off; off += (size_t)NTOK * 2 * DI;
    float* xc     = ws + off; off += (size_t)NTOK * DI;
    float* xdb    = ws + off; off += (size_t)NTOK * 44;
    float* ylocal = ws + off; off += (size_t)NTOK * DI;
    float* dtcum  = ws + off; off += (size_t)NTOK * DI;
    float* hend   = ws + off; off += (size_t)BATCH * NCH * DI * S;
    float* hinit  = ws + off; off += (size_t)BATCH * NCH * DI * S;
    float* negA   = ws + off; off += (size_t)DEPTH * DI * S;
    unsigned short* bf_buf = (unsigned short*)(ws + off); off += (size_t)NTOK * DI / 2;
    unsigned short* w_in  = (unsigned short*)(ws + off); off += (size_t)DEPTH * 2 * DI * E / 2;
    unsigned short* w_x   = (unsigned short*)(ws + off); off += (size_t)DEPTH * 44 * DI / 2 + 16;
    unsigned short* w_out = (unsigned short*)(ws + off); off += (size_t)DEPTH * E * DI / 2;

    unsigned short* hn_bf = bf_buf;   // [NTOK, E]
    unsigned short* xc_bf = bf_buf;   // [NTOK, DI]
    unsigned short* y_bf  = bf_buf;   // [NTOK, DI]

    // all weight conversions + negA in one kernel
    {
        int ntot = DEPTH * (2 * DI * E + 44 * DI + E * DI + DI * S);
        k_prep<<<(ntot + 255) / 256, 256, 0, stream>>>(in_proj_w, x_proj_w, out_proj_w, A_log,
                                                       w_in, w_x, w_out, negA);
    }

    // K0: embed
    k_embed<<<(NTOK * E) / 256, 256, 0, stream>>>(imgs, patch_w, patch_b, cls_token,
                                                  pos_embed, cnn_w, cnn_b, resid);

    for (int i = 0; i < DEPTH; i++) {
        if (i == 0)
            k_rmsnorm<false><<<NTOK / 4, 256, 0, stream>>>(hidden, resid, hn_bf, norm_w + i * E);
        else
            k_rmsnorm<true><<<NTOK / 4, 256, 0, stream>>>(hidden, resid, hn_bf, norm_w + i * E);

        // in_proj: [NTOK,192]bf16 x [768,192]bf16^T -> xz f32 [NTOK,768]
        {
            dim3 g((2 * DI) / 128, (NTOK + 127) / 128);
            k_gemm_bf16<128, 128><<<g, 256, 0, stream>>>(hn_bf, w_in + (size_t)i * 2 * DI * E,
                                                         xz, NTOK, 2 * DI, E);
        }
        // causal conv4 + silu -> xc f32 + bf16
        k_conv<<<(NTOK * DI) / 256, 256, 0, stream>>>(xz, conv_w + (size_t)i * DI * 4,
                                                      conv_b + (size_t)i * DI, xc, xc_bf);
        // x_proj: [NTOK,384]bf16 x [44,384]bf16^T -> xdb f32 [NTOK,44]
        {
            dim3 g(1, NTOK / 32);
            k_gemm_bf16<32, 64><<<g, 256, 0, stream>>>(xc_bf, w_x + (size_t)i * 44 * DI, xdb,
                                                       NTOK, 44, DI);
        }
        // chunked scan: local scan (dt_proj fused, n-split) -> combine -> fixup
        {
            const float* nA = negA + (size_t)i * DI * S;
            dim3 g(NCH, BATCH);
            k_scanA<<<g, 2 * DI, 0, stream>>>(xc, xdb, nA, dt_proj_w + (size_t)i * DI * R,
                                              dt_proj_b + (size_t)i * DI,
                                              Dskip + (size_t)i * DI, ylocal, dtcum, hend);
            k_scanB<<<(BATCH * DI + 255) / 256, 256, 0, stream>>>(hend, dtcum, nA, hinit);
            k_fixup<<<(NTOK * DI + 255) / 256, 256, 0, stream>>>(xz, xdb, nA, hinit,
                                                                 ylocal, dtcum, y_bf);
        }
        // out_proj: [NTOK,384]bf16 x [192,384]bf16^T -> hidden f32 [NTOK,192]
        {
            dim3 g(E / 64, (NTOK + 127) / 128);
            k_gemm_bf16<128, 64><<<g, 256, 0, stream>>>(y_bf, w_out + (size_t)i * E * DI,
                                                        hidden, NTOK, E, DI);
        }
    }

    k_head<<<BATCH, 64, 0, stream>>>(resid, hidden, norm_f_w, head_w, head_b, (float*)d_out);
}

// Round 6
// 959.839 us; speedup vs baseline: 1.0246x; 1.0246x over previous
//
#include <hip/hip_runtime.h>
#include <math.h>

#define E 192
#define DI 384
#define S 16
#define R 12
#define DEPTH 4
#define P 400
#define NC 20
#define BATCH 32
#define L 401
#define NTOK (BATCH * L)   // 12832
#define CH 32
#define NCH 13             // ceil(401/32)

using short8 = __attribute__((ext_vector_type(8))) short;
using float4v = __attribute__((ext_vector_type(4))) float;

__device__ __forceinline__ float siluf(float x) {
    return x / (1.f + __expf(-x));
}
__device__ __forceinline__ float softplusf(float x) {
    return (x > 20.f) ? x : log1pf(__expf(x));
}
// f32 -> bf16 round-to-nearest-even (bit-level; no __hip_bfloat16 dep)
__device__ __forceinline__ unsigned short f2bf(float x) {
    unsigned int u = __float_as_uint(x);
    unsigned int r = 0x7fffu + ((u >> 16) & 1u);
    return (unsigned short)((u + r) >> 16);
}
// is a[n] == (n+1)*a[0] (approx)? -> allows exp(dt*a_n) = e1^(n+1) pow-chain
__device__ __forceinline__ bool geom_check(const float* a) {
    bool ok = true;
#pragma unroll
    for (int n = 1; n < S; n++)
        ok = ok && (fabsf(a[n] - (float)(n + 1) * a[0]) <= 1e-5f * fabsf(a[n]));
    return ok;
}

// ---------------------------------------------------------------------------
// K0: patch embed + pos + depthwise conv3 + cls token  -> resid[b,l,e]
// ---------------------------------------------------------------------------
__global__ void k_embed(const float* __restrict__ imgs, const float* __restrict__ patch_w,
                        const float* __restrict__ patch_b, const float* __restrict__ cls_token,
                        const float* __restrict__ pos_embed, const float* __restrict__ cnn_w,
                        const float* __restrict__ cnn_b, float* __restrict__ resid) {
    int idx = blockIdx.x * blockDim.x + threadIdx.x;
    if (idx >= NTOK * E) return;
    int e = idx % E;
    int bl = idx / E;
    int l = bl % L;
    int b = bl / L;
    float out;
    if (l == P) {
        out = cls_token[e] + pos_embed[(size_t)P * E + e];
    } else {
        float w0 = patch_w[e * 4 + 0], w1 = patch_w[e * 4 + 1];
        float w2 = patch_w[e * 4 + 2], w3 = patch_w[e * 4 + 3];
        float pb = patch_b[e];
        const float* ib = imgs + (size_t)b * 1600;
        auto xe = [&](int ll) -> float {
            const float* ip = ib + ll * 4;
            return ip[0] * w0 + ip[1] * w1 + ip[2] * w2 + ip[3] * w3 + pb +
                   pos_embed[(size_t)ll * E + e];
        };
        float c0 = cnn_w[e * 3 + 0], c1 = cnn_w[e * 3 + 1], c2 = cnn_w[e * 3 + 2];
        float acc = cnn_b[e] + xe(l) * c1;
        if (l > 0) acc += xe(l - 1) * c0;
        if (l < P - 1) acc += xe(l + 1) * c2;
        out = acc;
    }
    resid[idx] = out;
}

// ---------------------------------------------------------------------------
// K1: (optional resid += hidden) then hn = rmsnorm(resid)*w -> bf16
// ---------------------------------------------------------------------------
template <bool ADD>
__global__ void k_rmsnorm(const float* __restrict__ hidden, float* __restrict__ resid,
                          unsigned short* __restrict__ hn, const float* __restrict__ w) {
    int wave = blockIdx.x * (blockDim.x >> 6) + (threadIdx.x >> 6);
    int lane = threadIdx.x & 63;
    if (wave >= NTOK) return;
    size_t base = (size_t)wave * E;
    float v[3];
    float ss = 0.f;
#pragma unroll
    for (int j = 0; j < 3; j++) {
        int e = lane + j * 64;
        float r = resid[base + e];
        if (ADD) {
            r += hidden[base + e];
            resid[base + e] = r;
        }
        v[j] = r;
        ss += r * r;
    }
#pragma unroll
    for (int off = 32; off > 0; off >>= 1) ss += __shfl_xor(ss, off, 64);
    float scale = rsqrtf(ss * (1.f / (float)E) + 1e-5f);
#pragma unroll
    for (int j = 0; j < 3; j++) {
        int e = lane + j * 64;
        hn[base + e] = f2bf(v[j] * scale * w[e]);
    }
}

// ---------------------------------------------------------------------------
// K_prep: all weight bf16 conversions + negA in one kernel
// ---------------------------------------------------------------------------
__global__ void k_prep(const float* __restrict__ in_proj_w, const float* __restrict__ x_proj_w,
                       const float* __restrict__ out_proj_w, const float* __restrict__ A_log,
                       unsigned short* __restrict__ w_in, unsigned short* __restrict__ w_x,
                       unsigned short* __restrict__ w_out, float* __restrict__ negA) {
    const int n1 = DEPTH * 2 * DI * E;
    const int n2 = DEPTH * 44 * DI;
    const int n3 = DEPTH * E * DI;
    const int n4 = DEPTH * DI * S;
    int idx = blockIdx.x * blockDim.x + threadIdx.x;
    if (idx < n1) {
        w_in[idx] = f2bf(in_proj_w[idx]);
    } else if (idx < n1 + n2) {
        int i = idx - n1;
        w_x[i] = f2bf(x_proj_w[i]);
    } else if (idx < n1 + n2 + n3) {
        int i = idx - n1 - n2;
        w_out[i] = f2bf(out_proj_w[i]);
    } else if (idx < n1 + n2 + n3 + n4) {
        int i = idx - n1 - n2 - n3;
        negA[i] = -__expf(A_log[i]);
    }
}

// ---------------------------------------------------------------------------
// K2: bf16 MFMA GEMM  C[M,N](f32) = A[M,K](bf16) * W[N,K](bf16)^T
// block 256 (4 waves, 2x2 over (M,N)), tile BM x BN, BK=64.
// ---------------------------------------------------------------------------
template <int BM, int BN>
__global__ __launch_bounds__(256) void k_gemm_bf16(const unsigned short* __restrict__ A,
                                                   const unsigned short* __restrict__ W,
                                                   float* __restrict__ C, int M, int N, int K) {
    constexpr int BK = 64, PADK = BK + 8;
    constexpr int MT = BM / 32, NT = BN / 32;
    __shared__ unsigned short As[BM][PADK];
    __shared__ unsigned short Bs[BN][PADK];
    int tid = threadIdx.x;
    int m0 = blockIdx.y * BM, n0 = blockIdx.x * BN;
    int wave = tid >> 6, lane = tid & 63;
    int row16 = lane & 15, quad = lane >> 4;
    int wm0 = (wave >> 1) * (BM / 2), wn0 = (wave & 1) * (BN / 2);

    float4v acc[MT][NT];
#pragma unroll
    for (int i = 0; i < MT; i++)
#pragma unroll
        for (int j = 0; j < NT; j++) acc[i][j] = (float4v){0.f, 0.f, 0.f, 0.f};

    for (int k0 = 0; k0 < K; k0 += BK) {
#pragma unroll
        for (int p = 0; p < MT; p++) {
            int idx = (p * 256 + tid) * 8;
            int row = idx / BK, col = idx % BK;
            int gm = m0 + row;
            short8 v;
            if (gm < M)
                v = *(const short8*)&A[(size_t)gm * K + k0 + col];
            else
                v = (short8)0;
            *(short8*)&As[row][col] = v;
        }
#pragma unroll
        for (int p = 0; p < NT; p++) {
            int idx = (p * 256 + tid) * 8;
            int row = idx / BK, col = idx % BK;
            int gn = n0 + row;
            short8 v;
            if (gn < N)
                v = *(const short8*)&W[(size_t)gn * K + k0 + col];
            else
                v = (short8)0;
            *(short8*)&Bs[row][col] = v;
        }
        __syncthreads();
#pragma unroll
        for (int kk = 0; kk < BK; kk += 32) {
            int koff = kk + quad * 8;
            short8 af[MT], bfr[NT];
#pragma unroll
            for (int i = 0; i < MT; i++)
                af[i] = *(const short8*)&As[wm0 + i * 16 + row16][koff];
#pragma unroll
            for (int j = 0; j < NT; j++)
                bfr[j] = *(const short8*)&Bs[wn0 + j * 16 + row16][koff];
#pragma unroll
            for (int i = 0; i < MT; i++)
#pragma unroll
                for (int j = 0; j < NT; j++)
                    acc[i][j] = __builtin_amdgcn_mfma_f32_16x16x32_bf16(af[i], bfr[j],
                                                                        acc[i][j], 0, 0, 0);
        }
        __syncthreads();
    }
#pragma unroll
    for (int i = 0; i < MT; i++) {
#pragma unroll
        for (int j = 0; j < NT; j++) {
#pragma unroll
            for (int r = 0; r < 4; r++) {
                int m = m0 + wm0 + i * 16 + quad * 4 + r;
                int n = n0 + wn0 + j * 16 + row16;
                if (m < M && n < N) C[(size_t)m * N + n] = acc[i][j][r];
            }
        }
    }
}

// ---------------------------------------------------------------------------
// K3: causal depthwise conv4 + SiLU over xm = xz[..., :DI] -> xc (f32 + bf16)
// ---------------------------------------------------------------------------
__global__ void k_conv(const float* __restrict__ xz, const float* __restrict__ cw,
                       const float* __restrict__ cb, float* __restrict__ xc,
                       unsigned short* __restrict__ xc_bf) {
    int idx = blockIdx.x * blockDim.x + threadIdx.x;
    if (idx >= NTOK * DI) return;
    int d = idx % DI;
    int bl = idx / DI;
    int l = bl % L;
    int b = bl / L;
    const float* base = xz + (size_t)b * L * (2 * DI) + d;
    float acc = cb[d];
#pragma unroll
    for (int k = 0; k < 4; k++) {
        int ll = l - 3 + k;
        if (ll >= 0) acc += base[(size_t)ll * (2 * DI)] * cw[d * 4 + k];
    }
    float v = siluf(acc);
    xc[idx] = v;
    xc_bf[idx] = f2bf(v);
}

// ---------------------------------------------------------------------------
// K_dtpre: dt = softplus(xdb[:, :12] @ dtw^T + dtb); e1 = exp(a0 * dt).
// Fully parallel; removes all transcendentals from the serial scan loop.
// ---------------------------------------------------------------------------
__global__ void k_dtpre(const float* __restrict__ xdb, const float* __restrict__ dtw,
                        const float* __restrict__ dtb, const float* __restrict__ negA,
                        float* __restrict__ dt, float* __restrict__ e1) {
    int idx = blockIdx.x * blockDim.x + threadIdx.x;
    if (idx >= NTOK * DI) return;
    int d = idx % DI;
    int tok = idx / DI;
    const float* xr = xdb + (size_t)tok * 44;
    const float* wr = dtw + (size_t)d * R;
    float acc = dtb[d];
#pragma unroll
    for (int r = 0; r < R; r++) acc += xr[r] * wr[r];
    float dtv = softplusf(acc);
    dt[idx] = dtv;
    e1[idx] = __expf(negA[d * S] * dtv);
}

// ---------------------------------------------------------------------------
// K4a: chunk-local scan; no transcendentals in loop when a_n=(n+1)a0 (checked).
// Emits per-token y_local (C.h_local + u*D) and dtcum, plus chunk h_end.
// grid (NCH, BATCH) x 384 threads (d per thread).
// ---------------------------------------------------------------------------
__global__ __launch_bounds__(384) void k_scanA(
        const float* __restrict__ xc, const float* __restrict__ xdb,
        const float* __restrict__ dt, const float* __restrict__ e1,
        const float* __restrict__ negA, const float* __restrict__ Dskip,
        float* __restrict__ ylocal, float* __restrict__ dtcum,
        float* __restrict__ hend) {
    int d = threadIdx.x;
    int ch = blockIdx.x;
    int b = blockIdx.y;
    int t0 = ch * CH;
    int t1 = min(t0 + CH, L);
    float a[S];
#pragma unroll
    for (int n = 0; n < S; n++) a[n] = negA[d * S + n];
    bool fast = geom_check(a);
    float dsk = Dskip[d];
    float h[S] = {};
    float dts = 0.f;
    for (int t = t0; t < t1; t++) {
        size_t tok = (size_t)b * L + t;
        const float* row = xdb + tok * 44;   // wave-uniform -> s_loads
        float dtv = dt[tok * DI + d];
        float e1v = e1[tok * DI + d];
        dts += dtv;
        float u = xc[tok * DI + d];
        float dtu = dtv * u;
        float y = u * dsk;
        if (fast) {
            float p = e1v;
#pragma unroll
            for (int n = 0; n < S; n++) {
                h[n] = p * h[n] + dtu * row[R + n];
                y += h[n] * row[R + S + n];
                p *= e1v;
            }
        } else {
#pragma unroll
            for (int n = 0; n < S; n++) {
                float dA = __expf(dtv * a[n]);
                h[n] = dA * h[n] + dtu * row[R + n];
                y += h[n] * row[R + S + n];
            }
        }
        ylocal[tok * DI + d] = y;
        dtcum[tok * DI + d] = dts;
    }
    size_t o = (((size_t)b * NCH + ch) * DI + d) * S;
#pragma unroll
    for (int n = 0; n < S; n++) hend[o + n] = h[n];
}

// ---------------------------------------------------------------------------
// K4b: combine chunk prefixes serially (NCH chunks) -> h_init per chunk.
// ---------------------------------------------------------------------------
__global__ void k_scanB(const float* __restrict__ hend, const float* __restrict__ dtcum,
                        const float* __restrict__ negA, float* __restrict__ hinit) {
    int idx = blockIdx.x * blockDim.x + threadIdx.x;
    if (idx >= BATCH * DI) return;
    int d = idx % DI;
    int b = idx / DI;
    float a[S];
#pragma unroll
    for (int n = 0; n < S; n++) a[n] = negA[d * S + n];
    bool fast = geom_check(a);
    float h[S] = {};
    for (int ch = 0; ch < NCH; ch++) {
        size_t o = (((size_t)b * NCH + ch) * DI + d) * S;
#pragma unroll
        for (int n = 0; n < S; n++) hinit[o + n] = h[n];
        int tlast = min(ch * CH + CH, L) - 1;
        float dts = dtcum[((size_t)b * L + tlast) * DI + d];
        if (fast) {
            float e1c = __expf(a[0] * dts);
            float p = e1c;
#pragma unroll
            for (int n = 0; n < S; n++) {
                h[n] = p * h[n] + hend[o + n];
                p *= e1c;
            }
        } else {
#pragma unroll
            for (int n = 0; n < S; n++) h[n] = __expf(dts * a[n]) * h[n] + hend[o + n];
        }
    }
}

// ---------------------------------------------------------------------------
// K4c: fully-parallel fixup: y = (y_local + sum_n c_n exp(a_n dtcum) h0_n)
//      * silu(z)  -> bf16. One thread per (tok,d).
// ---------------------------------------------------------------------------
__global__ void k_fixup(const float* __restrict__ xz, const float* __restrict__ xdb,
                        const float* __restrict__ negA, const float* __restrict__ hinit,
                        const float* __restrict__ ylocal, const float* __restrict__ dtcum,
                        unsigned short* __restrict__ y_bf) {
    int idx = blockIdx.x * blockDim.x + threadIdx.x;
    if (idx >= NTOK * DI) return;
    int d = idx % DI;
    int tok = idx / DI;
    int l = tok % L;
    int b = tok / L;
    int ch = l / CH;  // wave-uniform (DI divisible by 64)
    float y = ylocal[idx];
    if (ch != 0) {
        float a[S];
#pragma unroll
        for (int n = 0; n < S; n++) a[n] = negA[d * S + n];
        bool fast = geom_check(a);
        float dts = dtcum[idx];
        const float* h0 = hinit + (((size_t)b * NCH + ch) * DI + d) * S;
        const float* cv = xdb + (size_t)tok * 44 + R + S;
        float corr = 0.f;
        if (fast) {
            float e1c = __expf(a[0] * dts);
            float p = e1c;
#pragma unroll
            for (int n = 0; n < S; n++) {
                corr += cv[n] * p * h0[n];
                p *= e1c;
            }
        } else {
#pragma unroll
            for (int n = 0; n < S; n++) corr += cv[n] * __expf(a[n] * dts) * h0[n];
        }
        y += corr;
    }
    float z = xz[(size_t)tok * (2 * DI) + DI + d];
    y_bf[idx] = f2bf(y * siluf(z));
}

// ---------------------------------------------------------------------------
// K5: final rmsnorm of token 400 of (resid+hidden), then head matmul -> out
// ---------------------------------------------------------------------------
__global__ void k_head(const float* __restrict__ resid, const float* __restrict__ hidden,
                       const float* __restrict__ norm_f_w, const float* __restrict__ head_w,
                       const float* __restrict__ head_b, float* __restrict__ out) {
    __shared__ float v[E];
    int b = blockIdx.x;
    int lane = threadIdx.x;
    size_t base = ((size_t)b * L + P) * E;
    float loc[3];
    float ss = 0.f;
#pragma unroll
    for (int j = 0; j < 3; j++) {
        int e = lane + j * 64;
        float x = resid[base + e] + hidden[base + e];
        loc[j] = x;
        ss += x * x;
    }
#pragma unroll
    for (int off = 32; off > 0; off >>= 1) ss += __shfl_xor(ss, off, 64);
    float scale = rsqrtf(ss * (1.f / (float)E) + 1e-5f);
#pragma unroll
    for (int j = 0; j < 3; j++) {
        int e = lane + j * 64;
        v[e] = loc[j] * scale * norm_f_w[e];
    }
    __syncthreads();
    if (lane < NC) {
        float acc = head_b[lane];
        for (int e = 0; e < E; e++) acc += v[e] * head_w[lane * E + e];
        out[b * NC + lane] = acc;
    }
}

// ---------------------------------------------------------------------------
extern "C" void kernel_launch(void* const* d_in, const int* in_sizes, int n_in,
                              void* d_out, int out_size, void* d_ws, size_t ws_size,
                              hipStream_t stream) {
    const float* imgs      = (const float*)d_in[0];
    const float* patch_w   = (const float*)d_in[1];
    const float* patch_b   = (const float*)d_in[2];
    const float* cls_token = (const float*)d_in[3];
    const float* pos_embed = (const float*)d_in[4];
    const float* cnn_w     = (const float*)d_in[5];
    const float* cnn_b     = (const float*)d_in[6];
    const float* norm_w    = (const float*)d_in[7];
    const float* in_proj_w = (const float*)d_in[8];
    const float* conv_w    = (const float*)d_in[9];
    const float* conv_b    = (const float*)d_in[10];
    const float* x_proj_w  = (const float*)d_in[11];
    const float* dt_proj_w = (const float*)d_in[12];
    const float* dt_proj_b = (const float*)d_in[13];
    const float* A_log     = (const float*)d_in[14];
    const float* Dskip     = (const float*)d_in[15];
    const float* out_proj_w= (const float*)d_in[16];
    const float* norm_f_w  = (const float*)d_in[17];
    const float* head_w    = (const float*)d_in[18];
    const float* head_b    = (const float*)d_in[19];

    float* ws = (float*)d_ws;
    size_t off = 0;
    float* resid  = ws + off; off += (size_t)NTOK * E;
    float* hidden = ws + off; off += (size_t)NTOK * E;
    float* xz     = ws + off; off += (size_t)NTOK * 2 * DI;
    float* xc     = ws + off; off += (size_t)NTOK * DI;
    float* xdb    = ws + off; off += (size_t)NTOK * 44;
    float* dt     = ws + off; off += (size_t)NTOK * DI;
    float* e1     = ws + off; off += (size_t)NTOK * DI;
    float* ylocal = ws + off; off += (size_t)NTOK * DI;
    float* dtcum  = ws + off; off += (size_t)NTOK * DI;
    float* hend   = ws + off; off += (size_t)BATCH * NCH * DI * S;
    float* hinit  = ws + off; off += (size_t)BATCH * NCH * DI * S;
    float* negA   = ws + off; off += (size_t)DEPTH * DI * S;
    unsigned short* bf_buf = (unsigned short*)(ws + off); off += (size_t)NTOK * DI / 2;
    unsigned short* w_in  = (unsigned short*)(ws + off); off += (size_t)DEPTH * 2 * DI * E / 2;
    unsigned short* w_x   = (unsigned short*)(ws + off); off += (size_t)DEPTH * 44 * DI / 2 + 16;
    unsigned short* w_out = (unsigned short*)(ws + off); off += (size_t)DEPTH * E * DI / 2;

    unsigned short* hn_bf = bf_buf;   // [NTOK, E]
    unsigned short* xc_bf = bf_buf;   // [NTOK, DI]
    unsigned short* y_bf  = bf_buf;   // [NTOK, DI]

    {
        int ntot = DEPTH * (2 * DI * E + 44 * DI + E * DI + DI * S);
        k_prep<<<(ntot + 255) / 256, 256, 0, stream>>>(in_proj_w, x_proj_w, out_proj_w, A_log,
                                                       w_in, w_x, w_out, negA);
    }

    k_embed<<<(NTOK * E) / 256, 256, 0, stream>>>(imgs, patch_w, patch_b, cls_token,
                                                  pos_embed, cnn_w, cnn_b, resid);

    for (int i = 0; i < DEPTH; i++) {
        if (i == 0)
            k_rmsnorm<false><<<NTOK / 4, 256, 0, stream>>>(hidden, resid, hn_bf, norm_w + i * E);
        else
            k_rmsnorm<true><<<NTOK / 4, 256, 0, stream>>>(hidden, resid, hn_bf, norm_w + i * E);

        // in_proj: [NTOK,192]bf16 x [768,192]bf16^T -> xz f32 [NTOK,768]
        {
            dim3 g((2 * DI) / 64, (NTOK + 127) / 128);
            k_gemm_bf16<128, 64><<<g, 256, 0, stream>>>(hn_bf, w_in + (size_t)i * 2 * DI * E,
                                                        xz, NTOK, 2 * DI, E);
        }
        // causal conv4 + silu -> xc f32 + bf16
        k_conv<<<(NTOK * DI) / 256, 256, 0, stream>>>(xz, conv_w + (size_t)i * DI * 4,
                                                      conv_b + (size_t)i * DI, xc, xc_bf);
        // x_proj: [NTOK,384]bf16 x [44,384]bf16^T -> xdb f32 [NTOK,44]
        {
            dim3 g(1, NTOK / 32);
            k_gemm_bf16<32, 64><<<g, 256, 0, stream>>>(xc_bf, w_x + (size_t)i * 44 * DI, xdb,
                                                       NTOK, 44, DI);
        }
        const float* nA = negA + (size_t)i * DI * S;
        // dt_proj + softplus + e1=exp(a0*dt): fully parallel
        k_dtpre<<<(NTOK * DI) / 256, 256, 0, stream>>>(xdb, dt_proj_w + (size_t)i * DI * R,
                                                       dt_proj_b + (size_t)i * DI, nA, dt, e1);
        // chunked scan: local scan -> chunk combine -> parallel fixup
        {
            dim3 g(NCH, BATCH);
            k_scanA<<<g, DI, 0, stream>>>(xc, xdb, dt, e1, nA, Dskip + (size_t)i * DI,
                                          ylocal, dtcum, hend);
            k_scanB<<<(BATCH * DI + 255) / 256, 256, 0, stream>>>(hend, dtcum, nA, hinit);
            k_fixup<<<(NTOK * DI + 255) / 256, 256, 0, stream>>>(xz, xdb, nA, hinit,
                                                                 ylocal, dtcum, y_bf);
        }
        // out_proj: [NTOK,384]bf16 x [192,384]bf16^T -> hidden f32 [NTOK,192]
        {
            dim3 g(E / 64, (NTOK + 63) / 64);
            k_gemm_bf16<64, 64><<<g, 256, 0, stream>>>(y_bf, w_out + (size_t)i * E * DI,
                                                       hidden, NTOK, E, DI);
        }
    }

    k_head<<<BATCH, 64, 0, stream>>>(resid, hidden, norm_f_w, head_w, head_b, (float*)d_out);
}

// Round 7
// 772.664 us; speedup vs baseline: 1.2729x; 1.2422x over previous
//
#include <hip/hip_runtime.h>
#include <math.h>

#define E 192
#define DI 384
#define S 16
#define R 12
#define DEPTH 4
#define P 400
#define NC 20
#define BATCH 32
#define L 401
#define NTOK (BATCH * L)   // 12832
#define CH 32
#define NCH 13             // ceil(401/32)

using short8 = __attribute__((ext_vector_type(8))) short;
using float4v = __attribute__((ext_vector_type(4))) float;

__device__ __forceinline__ float siluf(float x) {
    return x / (1.f + __expf(-x));
}
__device__ __forceinline__ float softplusf(float x) {
    return (x > 20.f) ? x : log1pf(__expf(x));
}
// f32 -> bf16 round-to-nearest-even (bit-level; no __hip_bfloat16 dep)
__device__ __forceinline__ unsigned short f2bf(float x) {
    unsigned int u = __float_as_uint(x);
    unsigned int r = 0x7fffu + ((u >> 16) & 1u);
    return (unsigned short)((u + r) >> 16);
}

// ---------------------------------------------------------------------------
// K0: patch embed + pos + depthwise conv3 + cls token  -> resid[b,l,e]
// ---------------------------------------------------------------------------
__global__ void k_embed(const float* __restrict__ imgs, const float* __restrict__ patch_w,
                        const float* __restrict__ patch_b, const float* __restrict__ cls_token,
                        const float* __restrict__ pos_embed, const float* __restrict__ cnn_w,
                        const float* __restrict__ cnn_b, float* __restrict__ resid) {
    int idx = blockIdx.x * blockDim.x + threadIdx.x;
    if (idx >= NTOK * E) return;
    int e = idx % E;
    int bl = idx / E;
    int l = bl % L;
    int b = bl / L;
    float out;
    if (l == P) {
        out = cls_token[e] + pos_embed[(size_t)P * E + e];
    } else {
        float w0 = patch_w[e * 4 + 0], w1 = patch_w[e * 4 + 1];
        float w2 = patch_w[e * 4 + 2], w3 = patch_w[e * 4 + 3];
        float pb = patch_b[e];
        const float* ib = imgs + (size_t)b * 1600;
        auto xe = [&](int ll) -> float {
            const float* ip = ib + ll * 4;
            return ip[0] * w0 + ip[1] * w1 + ip[2] * w2 + ip[3] * w3 + pb +
                   pos_embed[(size_t)ll * E + e];
        };
        float c0 = cnn_w[e * 3 + 0], c1 = cnn_w[e * 3 + 1], c2 = cnn_w[e * 3 + 2];
        float acc = cnn_b[e] + xe(l) * c1;
        if (l > 0) acc += xe(l - 1) * c0;
        if (l < P - 1) acc += xe(l + 1) * c2;
        out = acc;
    }
    resid[idx] = out;
}

// ---------------------------------------------------------------------------
// K1: (optional resid += hidden) then hn = rmsnorm(resid)*w -> bf16
// ---------------------------------------------------------------------------
template <bool ADD>
__global__ void k_rmsnorm(const float* __restrict__ hidden, float* __restrict__ resid,
                          unsigned short* __restrict__ hn, const float* __restrict__ w) {
    int wave = blockIdx.x * (blockDim.x >> 6) + (threadIdx.x >> 6);
    int lane = threadIdx.x & 63;
    if (wave >= NTOK) return;
    size_t base = (size_t)wave * E;
    float v[3];
    float ss = 0.f;
#pragma unroll
    for (int j = 0; j < 3; j++) {
        int e = lane + j * 64;
        float r = resid[base + e];
        if (ADD) {
            r += hidden[base + e];
            resid[base + e] = r;
        }
        v[j] = r;
        ss += r * r;
    }
#pragma unroll
    for (int off = 32; off > 0; off >>= 1) ss += __shfl_xor(ss, off, 64);
    float scale = rsqrtf(ss * (1.f / (float)E) + 1e-5f);
#pragma unroll
    for (int j = 0; j < 3; j++) {
        int e = lane + j * 64;
        hn[base + e] = f2bf(v[j] * scale * w[e]);
    }
}

// ---------------------------------------------------------------------------
// K_prep: weight bf16 conversions + transposed negA ([layer][n][d]) +
// transposed dt weights ([layer][r][d]) in one kernel.
// ---------------------------------------------------------------------------
__global__ void k_prep(const float* __restrict__ in_proj_w, const float* __restrict__ x_proj_w,
                       const float* __restrict__ out_proj_w, const float* __restrict__ A_log,
                       const float* __restrict__ dt_proj_w,
                       unsigned short* __restrict__ w_in, unsigned short* __restrict__ w_x,
                       unsigned short* __restrict__ w_out, float* __restrict__ negA,
                       float* __restrict__ dtw_t) {
    const int n1 = DEPTH * 2 * DI * E;
    const int n2 = DEPTH * 44 * DI;
    const int n3 = DEPTH * E * DI;
    const int n4 = DEPTH * DI * S;
    const int n5 = DEPTH * DI * R;
    int idx = blockIdx.x * blockDim.x + threadIdx.x;
    if (idx < n1) {
        w_in[idx] = f2bf(in_proj_w[idx]);
    } else if (idx < n1 + n2) {
        int i = idx - n1;
        w_x[i] = f2bf(x_proj_w[i]);
    } else if (idx < n1 + n2 + n3) {
        int i = idx - n1 - n2;
        w_out[i] = f2bf(out_proj_w[i]);
    } else if (idx < n1 + n2 + n3 + n4) {
        int i = idx - n1 - n2 - n3;
        int layer = i / (DI * S);
        int rem = i % (DI * S);
        int n = rem / DI;
        int d = rem % DI;
        negA[i] = -__expf(A_log[(size_t)layer * DI * S + d * S + n]);
    } else if (idx < n1 + n2 + n3 + n4 + n5) {
        int i = idx - n1 - n2 - n3 - n4;
        int layer = i / (DI * R);
        int rem = i % (DI * R);
        int r = rem / DI;
        int d = rem % DI;
        dtw_t[i] = dt_proj_w[(size_t)layer * DI * R + d * R + r];
    }
}

// K_flag: per (layer,d): is a_n == (n+1)*a_0 for all n? -> pow-chain eligible
__global__ void k_flag(const float* __restrict__ negA, int* __restrict__ flag) {
    int idx = blockIdx.x * blockDim.x + threadIdx.x;
    if (idx >= DEPTH * DI) return;
    int layer = idx / DI;
    int d = idx % DI;
    const float* base = negA + (size_t)layer * DI * S;
    float a0 = base[d];
    bool ok = true;
#pragma unroll
    for (int n = 1; n < S; n++) {
        float an = base[n * DI + d];
        ok = ok && (fabsf(an - (float)(n + 1) * a0) <= 1e-5f * fabsf(an));
    }
    flag[idx] = ok ? 1 : 0;
}

// ---------------------------------------------------------------------------
// K2: bf16 MFMA GEMM  C[M,N](f32) = A[M,K](bf16) * W[N,K](bf16)^T
// block 256 (4 waves, 2x2 over (M,N)), tile BM x BN, BK=64.
// ---------------------------------------------------------------------------
template <int BM, int BN>
__global__ __launch_bounds__(256) void k_gemm_bf16(const unsigned short* __restrict__ A,
                                                   const unsigned short* __restrict__ W,
                                                   float* __restrict__ C, int M, int N, int K) {
    constexpr int BK = 64, PADK = BK + 8;
    constexpr int MT = BM / 32, NT = BN / 32;
    __shared__ unsigned short As[BM][PADK];
    __shared__ unsigned short Bs[BN][PADK];
    int tid = threadIdx.x;
    int m0 = blockIdx.y * BM, n0 = blockIdx.x * BN;
    int wave = tid >> 6, lane = tid & 63;
    int row16 = lane & 15, quad = lane >> 4;
    int wm0 = (wave >> 1) * (BM / 2), wn0 = (wave & 1) * (BN / 2);

    float4v acc[MT][NT];
#pragma unroll
    for (int i = 0; i < MT; i++)
#pragma unroll
        for (int j = 0; j < NT; j++) acc[i][j] = (float4v){0.f, 0.f, 0.f, 0.f};

    for (int k0 = 0; k0 < K; k0 += BK) {
#pragma unroll
        for (int p = 0; p < MT; p++) {
            int idx = (p * 256 + tid) * 8;
            int row = idx / BK, col = idx % BK;
            int gm = m0 + row;
            short8 v;
            if (gm < M)
                v = *(const short8*)&A[(size_t)gm * K + k0 + col];
            else
                v = (short8)0;
            *(short8*)&As[row][col] = v;
        }
#pragma unroll
        for (int p = 0; p < NT; p++) {
            int idx = (p * 256 + tid) * 8;
            int row = idx / BK, col = idx % BK;
            int gn = n0 + row;
            short8 v;
            if (gn < N)
                v = *(const short8*)&W[(size_t)gn * K + k0 + col];
            else
                v = (short8)0;
            *(short8*)&Bs[row][col] = v;
        }
        __syncthreads();
#pragma unroll
        for (int kk = 0; kk < BK; kk += 32) {
            int koff = kk + quad * 8;
            short8 af[MT], bfr[NT];
#pragma unroll
            for (int i = 0; i < MT; i++)
                af[i] = *(const short8*)&As[wm0 + i * 16 + row16][koff];
#pragma unroll
            for (int j = 0; j < NT; j++)
                bfr[j] = *(const short8*)&Bs[wn0 + j * 16 + row16][koff];
#pragma unroll
            for (int i = 0; i < MT; i++)
#pragma unroll
                for (int j = 0; j < NT; j++)
                    acc[i][j] = __builtin_amdgcn_mfma_f32_16x16x32_bf16(af[i], bfr[j],
                                                                        acc[i][j], 0, 0, 0);
        }
        __syncthreads();
    }
#pragma unroll
    for (int i = 0; i < MT; i++) {
#pragma unroll
        for (int j = 0; j < NT; j++) {
#pragma unroll
            for (int r = 0; r < 4; r++) {
                int m = m0 + wm0 + i * 16 + quad * 4 + r;
                int n = n0 + wn0 + j * 16 + row16;
                if (m < M && n < N) C[(size_t)m * N + n] = acc[i][j][r];
            }
        }
    }
}

// ---------------------------------------------------------------------------
// K3: causal depthwise conv4 + SiLU over xm = xz[..., :DI] -> xc (f32 + bf16)
// ---------------------------------------------------------------------------
__global__ void k_conv(const float* __restrict__ xz, const float* __restrict__ cw,
                       const float* __restrict__ cb, float* __restrict__ xc,
                       unsigned short* __restrict__ xc_bf) {
    int idx = blockIdx.x * blockDim.x + threadIdx.x;
    if (idx >= NTOK * DI) return;
    int d = idx % DI;
    int bl = idx / DI;
    int l = bl % L;
    int b = bl / L;
    const float* base = xz + (size_t)b * L * (2 * DI) + d;
    float acc = cb[d];
#pragma unroll
    for (int k = 0; k < 4; k++) {
        int ll = l - 3 + k;
        if (ll >= 0) acc += base[(size_t)ll * (2 * DI)] * cw[d * 4 + k];
    }
    float v = siluf(acc);
    xc[idx] = v;
    xc_bf[idx] = f2bf(v);
}

// ---------------------------------------------------------------------------
// K_dtpre: one block per token. dt = softplus(xdb_row . dtw_t + dtb);
// e1 = exp(a0*dt). Packed as float2 -> one dwordx2 in scanA.
// xdb row address depends only on blockIdx -> s_load broadcasts.
// ---------------------------------------------------------------------------
__global__ __launch_bounds__(384) void k_dtpre(
        const float* __restrict__ xdb, const float* __restrict__ dtw_t,
        const float* __restrict__ dtb, const float* __restrict__ negA_l,
        float2* __restrict__ dte1) {
    int tok = blockIdx.x;
    int d = threadIdx.x;
    const float* xr = xdb + (size_t)tok * 44;
    float acc = dtb[d];
#pragma unroll
    for (int r = 0; r < R; r++) acc += xr[r] * dtw_t[r * DI + d];
    float dtv = softplusf(acc);
    float e1 = __expf(negA_l[d] * dtv);
    dte1[(size_t)tok * DI + d] = make_float2(dtv, e1);
}

// ---------------------------------------------------------------------------
// K4a: chunk-local scan; no transcendentals in loop on fast path.
// Prefetches next step's dte1/xc before the h-chain. hend in [n][d] layout.
// grid (NCH, BATCH) x 384 threads (d per thread).
// ---------------------------------------------------------------------------
__global__ __launch_bounds__(384) void k_scanA(
        const float* __restrict__ xc, const float* __restrict__ xdb,
        const float2* __restrict__ dte1, const float* __restrict__ negA_l,
        const int* __restrict__ flag_l, const float* __restrict__ Dskip,
        float* __restrict__ ylocal, float* __restrict__ dtcum,
        float* __restrict__ hend) {
    int d = threadIdx.x;
    int ch = blockIdx.x;
    int b = blockIdx.y;
    int t0 = ch * CH;
    int t1 = min(t0 + CH, L);
    bool fast = __all(flag_l[d] != 0);
    float a[S];
    if (!fast) {
#pragma unroll
        for (int n = 0; n < S; n++) a[n] = negA_l[n * DI + d];
    }
    float dsk = Dskip[d];
    float h[S] = {};
    float dts = 0.f;
    size_t tok0 = (size_t)b * L + t0;
    float2 de = dte1[tok0 * DI + d];
    float u = xc[tok0 * DI + d];
    for (int t = t0; t < t1; t++) {
        size_t tok = (size_t)b * L + t;
        float dtv = de.x, e1v = de.y, uu = u;
        if (t + 1 < t1) {  // prefetch next step before the dependent chain
            de = dte1[(tok + 1) * DI + d];
            u = xc[(tok + 1) * DI + d];
        }
        const float* row = xdb + tok * 44;   // block-uniform-ish -> cached/scalar
        dts += dtv;
        float dtu = dtv * uu;
        float y = uu * dsk;
        if (fast) {
            float p = e1v;
#pragma unroll
            for (int n = 0; n < S; n++) {
                h[n] = p * h[n] + dtu * row[R + n];
                y += h[n] * row[R + S + n];
                p *= e1v;
            }
        } else {
#pragma unroll
            for (int n = 0; n < S; n++) {
                float dA = __expf(dtv * a[n]);
                h[n] = dA * h[n] + dtu * row[R + n];
                y += h[n] * row[R + S + n];
            }
        }
        ylocal[tok * DI + d] = y;
        dtcum[tok * DI + d] = dts;
    }
    float* he = hend + ((size_t)(b * NCH + ch) * S) * DI + d;
#pragma unroll
    for (int n = 0; n < S; n++) he[n * DI] = h[n];
}

// ---------------------------------------------------------------------------
// K4b: combine chunk prefixes serially (NCH chunks) -> h_init per chunk.
// hend/hinit in [b][ch][n][d] layout: all accesses coalesced across d.
// ---------------------------------------------------------------------------
__global__ void k_scanB(const float* __restrict__ hend, const float* __restrict__ dtcum,
                        const float* __restrict__ negA_l, const int* __restrict__ flag_l,
                        float* __restrict__ hinit) {
    int idx = blockIdx.x * blockDim.x + threadIdx.x;
    if (idx >= BATCH * DI) return;
    int d = idx % DI;
    int b = idx / DI;
    bool fast = __all(flag_l[d] != 0);
    float a[S];
#pragma unroll
    for (int n = 0; n < S; n++) a[n] = negA_l[n * DI + d];
    float h[S] = {};
    for (int ch = 0; ch < NCH; ch++) {
        size_t o = ((size_t)(b * NCH + ch) * S) * DI + d;
#pragma unroll
        for (int n = 0; n < S; n++) hinit[o + n * DI] = h[n];
        int tlast = min(ch * CH + CH, L) - 1;
        float dts = dtcum[((size_t)b * L + tlast) * DI + d];
        if (fast) {
            float e1c = __expf(a[0] * dts);
            float p = e1c;
#pragma unroll
            for (int n = 0; n < S; n++) {
                h[n] = p * h[n] + hend[o + n * DI];
                p *= e1c;
            }
        } else {
#pragma unroll
            for (int n = 0; n < S; n++) h[n] = __expf(dts * a[n]) * h[n] + hend[o + n * DI];
        }
    }
}

// ---------------------------------------------------------------------------
// K4c: fixup, one block per token: y = (y_local + sum_n c_n exp(a_n dtcum) h0_n)
//      * silu(z) -> bf16. cv row is block-uniform -> s_loads; h0 coalesced.
// ---------------------------------------------------------------------------
__global__ __launch_bounds__(384) void k_fixup(
        const float* __restrict__ xz, const float* __restrict__ xdb,
        const float* __restrict__ negA_l, const int* __restrict__ flag_l,
        const float* __restrict__ hinit, const float* __restrict__ ylocal,
        const float* __restrict__ dtcum, unsigned short* __restrict__ y_bf) {
    int tok = blockIdx.x;
    int d = threadIdx.x;
    int l = tok % L;
    int b = tok / L;
    int ch = l / CH;
    size_t idx = (size_t)tok * DI + d;
    float y = ylocal[idx];
    if (ch != 0) {
        bool fast = __all(flag_l[d] != 0);
        const float* h0 = hinit + ((size_t)(b * NCH + ch) * S) * DI + d;
        const float* cv = xdb + (size_t)tok * 44 + R + S;  // block-uniform
        float dts = dtcum[idx];
        float corr = 0.f;
        if (fast) {
            float e1c = __expf(negA_l[d] * dts);
            float p = e1c;
#pragma unroll
            for (int n = 0; n < S; n++) {
                corr += cv[n] * p * h0[n * DI];
                p *= e1c;
            }
        } else {
#pragma unroll
            for (int n = 0; n < S; n++)
                corr += cv[n] * __expf(negA_l[n * DI + d] * dts) * h0[n * DI];
        }
        y += corr;
    }
    float z = xz[(size_t)tok * (2 * DI) + DI + d];
    y_bf[idx] = f2bf(y * siluf(z));
}

// ---------------------------------------------------------------------------
// K5: final rmsnorm of token 400 of (resid+hidden), then head matmul -> out
// ---------------------------------------------------------------------------
__global__ void k_head(const float* __restrict__ resid, const float* __restrict__ hidden,
                       const float* __restrict__ norm_f_w, const float* __restrict__ head_w,
                       const float* __restrict__ head_b, float* __restrict__ out) {
    __shared__ float v[E];
    int b = blockIdx.x;
    int lane = threadIdx.x;
    size_t base = ((size_t)b * L + P) * E;
    float loc[3];
    float ss = 0.f;
#pragma unroll
    for (int j = 0; j < 3; j++) {
        int e = lane + j * 64;
        float x = resid[base + e] + hidden[base + e];
        loc[j] = x;
        ss += x * x;
    }
#pragma unroll
    for (int off = 32; off > 0; off >>= 1) ss += __shfl_xor(ss, off, 64);
    float scale = rsqrtf(ss * (1.f / (float)E) + 1e-5f);
#pragma unroll
    for (int j = 0; j < 3; j++) {
        int e = lane + j * 64;
        v[e] = loc[j] * scale * norm_f_w[e];
    }
    __syncthreads();
    if (lane < NC) {
        float acc = head_b[lane];
        for (int e = 0; e < E; e++) acc += v[e] * head_w[lane * E + e];
        out[b * NC + lane] = acc;
    }
}

// ---------------------------------------------------------------------------
extern "C" void kernel_launch(void* const* d_in, const int* in_sizes, int n_in,
                              void* d_out, int out_size, void* d_ws, size_t ws_size,
                              hipStream_t stream) {
    const float* imgs      = (const float*)d_in[0];
    const float* patch_w   = (const float*)d_in[1];
    const float* patch_b   = (const float*)d_in[2];
    const float* cls_token = (const float*)d_in[3];
    const float* pos_embed = (const float*)d_in[4];
    const float* cnn_w     = (const float*)d_in[5];
    const float* cnn_b     = (const float*)d_in[6];
    const float* norm_w    = (const float*)d_in[7];
    const float* in_proj_w = (const float*)d_in[8];
    const float* conv_w    = (const float*)d_in[9];
    const float* conv_b    = (const float*)d_in[10];
    const float* x_proj_w  = (const float*)d_in[11];
    const float* dt_proj_w = (const float*)d_in[12];
    const float* dt_proj_b = (const float*)d_in[13];
    const float* A_log     = (const float*)d_in[14];
    const float* Dskip     = (const float*)d_in[15];
    const float* out_proj_w= (const float*)d_in[16];
    const float* norm_f_w  = (const float*)d_in[17];
    const float* head_w    = (const float*)d_in[18];
    const float* head_b    = (const float*)d_in[19];

    float* ws = (float*)d_ws;
    size_t off = 0;
    float* resid  = ws + off; off += (size_t)NTOK * E;
    float* hidden = ws + off; off += (size_t)NTOK * E;
    float* xz     = ws + off; off += (size_t)NTOK * 2 * DI;
    float* xc     = ws + off; off += (size_t)NTOK * DI;
    float* xdb    = ws + off; off += (size_t)NTOK * 44;
    float* dte1   = ws + off; off += (size_t)NTOK * DI * 2;  // packed {dt,e1}
    float* ylocal = ws + off; off += (size_t)NTOK * DI;
    float* dtcum  = ws + off; off += (size_t)NTOK * DI;
    float* hend   = ws + off; off += (size_t)BATCH * NCH * DI * S;  // [b][ch][n][d]
    float* hinit  = ws + off; off += (size_t)BATCH * NCH * DI * S;  // [b][ch][n][d]
    float* negA   = ws + off; off += (size_t)DEPTH * DI * S;        // [layer][n][d]
    float* dtw_t  = ws + off; off += (size_t)DEPTH * DI * R;        // [layer][r][d]
    int*   gflag  = (int*)(ws + off); off += (size_t)DEPTH * DI;    // [layer][d]
    unsigned short* bf_buf = (unsigned short*)(ws + off); off += (size_t)NTOK * DI / 2;
    unsigned short* w_in  = (unsigned short*)(ws + off); off += (size_t)DEPTH * 2 * DI * E / 2;
    unsigned short* w_x   = (unsigned short*)(ws + off); off += (size_t)DEPTH * 44 * DI / 2 + 16;
    unsigned short* w_out = (unsigned short*)(ws + off); off += (size_t)DEPTH * E * DI / 2;

    unsigned short* hn_bf = bf_buf;   // [NTOK, E]
    unsigned short* xc_bf = bf_buf;   // [NTOK, DI]
    unsigned short* y_bf  = bf_buf;   // [NTOK, DI]

    {
        int ntot = DEPTH * (2 * DI * E + 44 * DI + E * DI + DI * S + DI * R);
        k_prep<<<(ntot + 255) / 256, 256, 0, stream>>>(in_proj_w, x_proj_w, out_proj_w, A_log,
                                                       dt_proj_w, w_in, w_x, w_out, negA,
                                                       dtw_t);
        k_flag<<<(DEPTH * DI + 255) / 256, 256, 0, stream>>>(negA, gflag);
    }

    k_embed<<<(NTOK * E) / 256, 256, 0, stream>>>(imgs, patch_w, patch_b, cls_token,
                                                  pos_embed, cnn_w, cnn_b, resid);

    for (int i = 0; i < DEPTH; i++) {
        if (i == 0)
            k_rmsnorm<false><<<NTOK / 4, 256, 0, stream>>>(hidden, resid, hn_bf, norm_w + i * E);
        else
            k_rmsnorm<true><<<NTOK / 4, 256, 0, stream>>>(hidden, resid, hn_bf, norm_w + i * E);

        // in_proj: [NTOK,192]bf16 x [768,192]bf16^T -> xz f32 [NTOK,768]
        {
            dim3 g((2 * DI) / 64, (NTOK + 127) / 128);
            k_gemm_bf16<128, 64><<<g, 256, 0, stream>>>(hn_bf, w_in + (size_t)i * 2 * DI * E,
                                                        xz, NTOK, 2 * DI, E);
        }
        // causal conv4 + silu -> xc f32 + bf16
        k_conv<<<(NTOK * DI) / 256, 256, 0, stream>>>(xz, conv_w + (size_t)i * DI * 4,
                                                      conv_b + (size_t)i * DI, xc, xc_bf);
        // x_proj: [NTOK,384]bf16 x [44,384]bf16^T -> xdb f32 [NTOK,44]
        {
            dim3 g(1, NTOK / 32);
            k_gemm_bf16<32, 64><<<g, 256, 0, stream>>>(xc_bf, w_x + (size_t)i * 44 * DI, xdb,
                                                       NTOK, 44, DI);
        }
        const float* nA = negA + (size_t)i * DI * S;
        const int* fl = gflag + (size_t)i * DI;
        // dt_proj + softplus + e1: block per token
        k_dtpre<<<NTOK, 384, 0, stream>>>(xdb, dtw_t + (size_t)i * DI * R,
                                          dt_proj_b + (size_t)i * DI, nA, (float2*)dte1);
        // chunked scan: local scan -> chunk combine -> parallel fixup
        {
            dim3 g(NCH, BATCH);
            k_scanA<<<g, DI, 0, stream>>>(xc, xdb, (const float2*)dte1, nA, fl,
                                          Dskip + (size_t)i * DI, ylocal, dtcum, hend);
            k_scanB<<<(BATCH * DI + 255) / 256, 256, 0, stream>>>(hend, dtcum, nA, fl, hinit);
            k_fixup<<<NTOK, 384, 0, stream>>>(xz, xdb, nA, fl, hinit, ylocal, dtcum, y_bf);
        }
        // out_proj: [NTOK,384]bf16 x [192,384]bf16^T -> hidden f32 [NTOK,192]
        {
            dim3 g(E / 64, (NTOK + 63) / 64);
            k_gemm_bf16<64, 64><<<g, 256, 0, stream>>>(y_bf, w_out + (size_t)i * E * DI,
                                                       hidden, NTOK, E, DI);
        }
    }

    k_head<<<BATCH, 64, 0, stream>>>(resid, hidden, norm_f_w, head_w, head_b, (float*)d_out);
}